// Round 18
// baseline (96.544 us; speedup 1.0000x reference)
//
#include <hip/hip_runtime.h>

#define M_TOTAL 8192
#define KDIM 1024
#define TASKS 20
#define SBUF 256

typedef __attribute__((ext_vector_type(4))) int i32x4;
typedef __attribute__((ext_vector_type(8))) int i32x8;
typedef __attribute__((ext_vector_type(16))) float f32x16;

__device__ __forceinline__ void gload_lds16(const void* g, char* l) {
  __builtin_amdgcn_global_load_lds((const __attribute__((address_space(1))) void*)g,
                                   (__attribute__((address_space(3))) void*)l, 16, 0, 0);
}

#define FENCE() asm volatile("" ::: "memory")
#define BAR() do { FENCE(); __builtin_amdgcn_s_barrier(); FENCE(); } while (0)
#define LGKM0() asm volatile("s_waitcnt lgkmcnt(0)" ::: "memory")
#define VMC(n) asm volatile("s_waitcnt vmcnt(" #n ")" ::: "memory")
#define SCHED0() __builtin_amdgcn_sched_barrier(0)
// All scale bytes = 0x7F (E8M0 exp 0 -> x1.0): plain fp8 GEMM at MX rate.
#define MFMA_(a, bb, c) \
  (c) = __builtin_amdgcn_mfma_scale_f32_32x32x64_f8f6f4((a), (bb), (c), 0, 0, \
                                                        0, 0x7F7F7F7F, 0, 0x7F7F7F7F)

// One block per row: L2-normalize a 1024-float row of X or W, emit fp8 e4m3
// (RNE via v_cvt_pk_fp8_f32). First 640 blocks also init out[] to -1e30 for
// the atomicMin combine (runs before gemm in stream order).
__global__ __launch_bounds__(256) void norm_rows_kernel(const float* __restrict__ X,
                                                        const float* __restrict__ W,
                                                        unsigned int* __restrict__ Xq,
                                                        unsigned int* __restrict__ Wq,
                                                        float* __restrict__ out) {
  const int row = blockIdx.x;
  const int tid = threadIdx.x;
  if (row < (M_TOTAL * TASKS) / 256) out[row * 256 + tid] = -1e30f;
  const float* in;
  unsigned int* outp;
  int r;
  if (row < M_TOTAL) { in = X; outp = Xq; r = row; }
  else               { in = W; outp = Wq; r = row - M_TOTAL; }
  const float4 v = ((const float4*)(in + (size_t)r * KDIM))[tid];
  float s = v.x * v.x + v.y * v.y + v.z * v.z + v.w * v.w;
#pragma unroll
  for (int off = 32; off >= 1; off >>= 1) s += __shfl_xor(s, off, 64);
  __shared__ float part[4];
  if ((tid & 63) == 0) part[tid >> 6] = s;
  __syncthreads();
  s = part[0] + part[1] + part[2] + part[3];
  const float sc = rsqrtf(s);
  int pk = __builtin_amdgcn_cvt_pk_fp8_f32(v.x * sc, v.y * sc, 0, false);
  pk = __builtin_amdgcn_cvt_pk_fp8_f32(v.z * sc, v.w * sc, pk, true);
  outp[(size_t)r * (KDIM / 4) + tid] = (unsigned int)pk;
}

// 128(M) x 128(N) x BK=128 fp8-MX tile, 32x32x64 shape (layouts HW-verified
// r13: absmax 0.0078). 256 thr = 4 waves (2M x 2N), wave tile 64x64 = 2x2
// 32x32, acc[2][2] f32x16. r16/r17 lean-register skeleton ((256,1),
// imm-offset addressing, #pragma unroll 1 K-loop, 16-B-slot swizzle,
// shufflevector fragment combine) = 104 arch regs, 2 blocks/CU.
// *** r17 fix: ONE barrier per K-tile. Alternating double-buffer: tile t
// reads buf t&1 and stages tile t+1 into buf ~(t&1) at the TOP of the tile
// (issue-early: HBM/L2 latency hides under ~1100 cyc of frag-reads+MFMA).
// The written buffer was last read at t-1, whose ds_reads completed before
// t-1's end barrier (MFMA lgkm waits + LGKM0 backstop) -> no read/overwrite
// hazard, so the r17 mid-tile drain barrier disappears. VMC(0) at tile end
// is cheap (waits on loads issued a full tile ago) and the single BAR then
// publishes buf t+1 to all waves. Barrier events 16 -> 8 per block. ***
// LDS per buf (32 KB at B_*32768): A [0,16K) 128-B rows, B [16K,32K).
// Swizzle: phys 16-B slot = (ks*4 + l2*2 + h) ^ (l31&7); 2 lanes/slot = free.
// Stage: thread t -> linear dest ii*4096 + t*16; source slot
// ((t&7) ^ ((t>>3)&7))*16 is the inverse permutation (rule #21).
// Half-task columns combined via uint atomicMin of negative floats (exact).
__global__ __launch_bounds__(256, 1) void gemm_min_kernel(const unsigned char* __restrict__ Xq,
                                                          const unsigned char* __restrict__ Wq,
                                                          float* __restrict__ out) {
  __shared__ __align__(32) char sm[66560];

  const int tid = threadIdx.x;
  const int lane = tid & 63;
  const int w = tid >> 6, wr = w >> 1, wc = w & 1;
  const int l31 = lane & 31, l2 = lane >> 5;
  const int l7 = l31 & 7;

  // XCD swizzle: 2560 blocks; xcd owns an 8-mblk stripe, mblk fastest, nblk slow.
  const int o = blockIdx.x;
  const int xcd = o & 7, i = o >> 3;        // i in [0,320)
  const int nblk = i >> 3;                   // 0..39
  const int mblk = xcd * 8 + (i & 7);        // 0..63
  const int rowBase = mblk * 128;
  const int col0 = nblk * 128;
  const int task = nblk >> 1;

  // staging source (inverse 16-B-slot swizzle, r13-proven)
  const int srow = tid >> 3;
  const int soff = ((tid & 7) ^ ((tid >> 3) & 7)) * 16;
  const unsigned char* pA = Xq + (size_t)(rowBase + srow) * KDIM + soff;
  const unsigned char* pB = Wq + (size_t)(col0 + srow) * KDIM + soff;

  // LDS read bases (8 VGPRs): per region x ks, lo/hi 16-B halves.
  // row = region + mi*32 + l31 (row&7 = l31&7); {buf, mi} via immediates.
  const int rowA = (wr * 64 + l31) * 128;
  const int rowB = 16384 + (wc * 64 + l31) * 128;
  const char* aL0 = sm + rowA + (((l2 * 2) ^ l7) * 16);
  const char* aH0 = sm + rowA + (((l2 * 2 + 1) ^ l7) * 16);
  const char* aL1 = sm + rowA + (((4 + l2 * 2) ^ l7) * 16);
  const char* aH1 = sm + rowA + (((4 + l2 * 2 + 1) ^ l7) * 16);
  const char* bL0 = sm + rowB + (((l2 * 2) ^ l7) * 16);
  const char* bH0 = sm + rowB + (((l2 * 2 + 1) ^ l7) * 16);
  const char* bL1 = sm + rowB + (((4 + l2 * 2) ^ l7) * 16);
  const char* bH1 = sm + rowB + (((4 + l2 * 2 + 1) ^ l7) * 16);

  f32x16 acc[2][2] = {};

  // 8 loads/thread/K-tile into buf B_: A chunks 0..3 (128 rows), B chunks 0..3
#define STG(B_, kB) do { \
    _Pragma("unroll") for (int ii = 0; ii < 4; ++ii) { \
      gload_lds16(pA + (size_t)ii * 32 * KDIM + (kB), sm + (B_) * 32768 + ii * 4096 + tid * 16); \
      gload_lds16(pB + (size_t)ii * 32 * KDIM + (kB), sm + (B_) * 32768 + 16384 + ii * 4096 + tid * 16); \
    } } while (0)

  // 32-B fragment: two b128 at swizzled slots, shufflevector combine (no UB)
#define LD32(dst, lo, hi, off_) do { \
    i32x4 lo_ = *(const i32x4*)((lo) + (off_)); \
    i32x4 hi_ = *(const i32x4*)((hi) + (off_)); \
    (dst) = __builtin_shufflevector(lo_, hi_, 0, 1, 2, 3, 4, 5, 6, 7); \
  } while (0)

#define KSTEP(B_, aL, aH, bL, bH) do { \
    i32x8 aF0, aF1, bF0, bF1; \
    LD32(aF0, aL, aH, (B_) * 32768); \
    LD32(aF1, aL, aH, (B_) * 32768 + 4096); \
    LD32(bF0, bL, bH, (B_) * 32768); \
    LD32(bF1, bL, bH, (B_) * 32768 + 4096); \
    __builtin_amdgcn_s_setprio(1); \
    MFMA_(aF0, bF0, acc[0][0]); MFMA_(aF0, bF1, acc[0][1]); \
    MFMA_(aF1, bF0, acc[1][0]); MFMA_(aF1, bF1, acc[1][1]); \
    __builtin_amdgcn_s_setprio(0); \
  } while (0)

  // Per K-tile t (buf B_ = t&1): {STG t+1 -> buf 1-B_ (issue early);
  //   ks0 + ks1 frag reads + MFMAs on buf B_; LGKM0 (reads consumed);
  //   VMC(0) (t+1 resident -- issued a full tile ago); ONE BAR}.
#define KTILE(B_, kB1) do { \
    STG(1 - (B_), kB1); \
    KSTEP(B_, aL0, aH0, bL0, bH0); \
    KSTEP(B_, aL1, aH1, bL1, bH1); \
    LGKM0(); SCHED0(); \
    VMC(0); SCHED0(); \
    BAR(); \
  } while (0)

  // prologue: tile0 -> buf0; drain; barrier
  STG(0, 0);
  VMC(0); SCHED0();
  BAR();

#pragma unroll 1
  for (int kt = 0; kt < 8; kt += 2) {
    const int k1 = (kt + 1) * 128;                       // kt+1 <= 7 always here
    const int k2 = (kt + 2 < 8) ? (kt + 2) * 128 : 0;    // wrap: harmless garbage
    KTILE(0, k1);
    KTILE(1, k2);
  }

  // loop ends with VMC(0)+BAR: nothing outstanding, LDS reusable (r5 race safe)

  // epilogue: per-row max-dot over 2 n-tiles + 32 col-lanes -> red -> atomic.
  // C/D layout (r13 HW-verified): col=lane&31, row=(reg&3)+8*(reg>>2)+4*l2.
  float (*red)[2] = (float (*)[2])(sm + 65536);  // outside staging regions
#pragma unroll
  for (int mi = 0; mi < 2; ++mi) {
#pragma unroll
    for (int r = 0; r < 16; ++r) {
      float v = fmaxf(acc[mi][0][r], acc[mi][1][r]);
      v = fmaxf(v, __shfl_xor(v, 1, 64));
      v = fmaxf(v, __shfl_xor(v, 2, 64));
      v = fmaxf(v, __shfl_xor(v, 4, 64));
      v = fmaxf(v, __shfl_xor(v, 8, 64));
      v = fmaxf(v, __shfl_xor(v, 16, 64));
      if (l31 == 0)
        red[wr * 64 + mi * 32 + (r & 3) + 8 * (r >> 2) + 4 * l2][wc] = v;
    }
  }
  BAR();
  if (tid < 128) {
    const float vv = fmaxf(red[tid][0], red[tid][1]);
    const float d = sqrtf(fmaxf(2.0f - 2.0f * vv, 1e-12f));
    // all published values negative: uint atomicMin == float max == -min dist
    atomicMin((unsigned int*)&out[(size_t)(rowBase + tid) * TASKS + task],
              __float_as_uint(-d));
  }
#undef KTILE
#undef KSTEP
#undef LD32
#undef STG
}

extern "C" void kernel_launch(void* const* d_in, const int* in_sizes, int n_in,
                              void* d_out, int out_size, void* d_ws, size_t ws_size,
                              hipStream_t stream) {
  const float* X = (const float*)d_in[0];   // (8192, 1024) fp32
  const float* W = (const float*)d_in[1];   // (5120, 1024) fp32
  float* out = (float*)d_out;               // (8192, 20) fp32

  unsigned char* Xq = (unsigned char*)d_ws;                          // 8.4 MB fp8
  unsigned char* Wq = Xq + (size_t)M_TOTAL * KDIM;                   // 5.2 MB fp8

  norm_rows_kernel<<<M_TOTAL + TASKS * SBUF, 256, 0, stream>>>(
      X, W, (unsigned int*)Xq, (unsigned int*)Wq, out);
  gemm_min_kernel<<<2560, 256, 0, stream>>>(Xq, Wq, out);
}

// Round 20
// 95.949 us; speedup vs baseline: 1.0062x; 1.0062x over previous
//
#include <hip/hip_runtime.h>

#define M_TOTAL 8192
#define KDIM 1024
#define TASKS 20
#define SBUF 256

typedef __attribute__((ext_vector_type(4))) int i32x4;
typedef __attribute__((ext_vector_type(8))) int i32x8;
typedef __attribute__((ext_vector_type(16))) float f32x16;

__device__ __forceinline__ void gload_lds16(const void* g, char* l) {
  __builtin_amdgcn_global_load_lds((const __attribute__((address_space(1))) void*)g,
                                   (__attribute__((address_space(3))) void*)l, 16, 0, 0);
}

#define FENCE() asm volatile("" ::: "memory")
#define BAR() do { FENCE(); __builtin_amdgcn_s_barrier(); FENCE(); } while (0)
#define LGKM0() asm volatile("s_waitcnt lgkmcnt(0)" ::: "memory")
#define VMC(n) asm volatile("s_waitcnt vmcnt(" #n ")" ::: "memory")
#define SCHED0() __builtin_amdgcn_sched_barrier(0)
// All scale bytes = 0x7F (E8M0 exp 0 -> x1.0): plain fp8 GEMM at MX rate.
#define MFMA_(a, bb, c) \
  (c) = __builtin_amdgcn_mfma_scale_f32_32x32x64_f8f6f4((a), (bb), (c), 0, 0, \
                                                        0, 0x7F7F7F7F, 0, 0x7F7F7F7F)

// One block per row: L2-normalize a 1024-float row of X or W, emit fp8 e4m3
// (RNE via v_cvt_pk_fp8_f32). First 640 blocks also init out[] to -1e30 for
// the atomicMin combine (runs before gemm in stream order).
__global__ __launch_bounds__(256) void norm_rows_kernel(const float* __restrict__ X,
                                                        const float* __restrict__ W,
                                                        unsigned int* __restrict__ Xq,
                                                        unsigned int* __restrict__ Wq,
                                                        float* __restrict__ out) {
  const int row = blockIdx.x;
  const int tid = threadIdx.x;
  if (row < (M_TOTAL * TASKS) / 256) out[row * 256 + tid] = -1e30f;
  const float* in;
  unsigned int* outp;
  int r;
  if (row < M_TOTAL) { in = X; outp = Xq; r = row; }
  else               { in = W; outp = Wq; r = row - M_TOTAL; }
  const float4 v = ((const float4*)(in + (size_t)r * KDIM))[tid];
  float s = v.x * v.x + v.y * v.y + v.z * v.z + v.w * v.w;
#pragma unroll
  for (int off = 32; off >= 1; off >>= 1) s += __shfl_xor(s, off, 64);
  __shared__ float part[4];
  if ((tid & 63) == 0) part[tid >> 6] = s;
  __syncthreads();
  s = part[0] + part[1] + part[2] + part[3];
  const float sc = rsqrtf(s);
  int pk = __builtin_amdgcn_cvt_pk_fp8_f32(v.x * sc, v.y * sc, 0, false);
  pk = __builtin_amdgcn_cvt_pk_fp8_f32(v.z * sc, v.w * sc, pk, true);
  outp[(size_t)r * (KDIM / 4) + tid] = (unsigned int)pk;
}

// 128(M) x 128(N) x BK=128 fp8-MX tile, 32x32x64 shape (layouts HW-verified
// r13: absmax 0.0078). 256 thr = 4 waves (2M x 2N), wave tile 64x64 = 2x2
// 32x32, acc[2][2] f32x16. r16 lean-register skeleton ((256,1), imm-offset
// addressing, #pragma unroll 1 K-loop) = 104 arch regs, 2 blocks/CU.
// 16-B-slot bank swizzle: phys = (ks*4 + l2*2 + h) ^ (l31&7) -> 8 slots,
// 2 lanes/slot (2-way = free, m136). Fragment = two b128 at slot and slot^1,
// combined by shufflevector (no typed stores - r10 TBAA lesson).
// LDS per buf (32 KB at B_*32768): A [0,16K) 128-B rows, B [16K,32K).
// Stage: thread t -> linear dest ii*4096 + t*16; source slot
// ((t&7) ^ ((t>>3)&7))*16 is the inverse permutation (rule #21, r13-proven).
// 8 K-tiles, 2-barrier KTILE, counted VMC(8) 2-deep ledger.
// Half-task columns combined via uint atomicMin of negative floats (exact).
// [r19 post-mortem: a 3-buffer never-drain port raced (absmax 0.18) despite a
// paper-correct ledger — sync-structure edits need race-screening (m152);
// this 2-barrier schedule is the session's verified optimum at 95.8 us.]
__global__ __launch_bounds__(256, 1) void gemm_min_kernel(const unsigned char* __restrict__ Xq,
                                                          const unsigned char* __restrict__ Wq,
                                                          float* __restrict__ out) {
  __shared__ __align__(32) char sm[66560];

  const int tid = threadIdx.x;
  const int lane = tid & 63;
  const int w = tid >> 6, wr = w >> 1, wc = w & 1;
  const int l31 = lane & 31, l2 = lane >> 5;
  const int l7 = l31 & 7;

  // XCD swizzle: 2560 blocks; xcd owns an 8-mblk stripe, mblk fastest, nblk slow.
  const int o = blockIdx.x;
  const int xcd = o & 7, i = o >> 3;        // i in [0,320)
  const int nblk = i >> 3;                   // 0..39
  const int mblk = xcd * 8 + (i & 7);        // 0..63
  const int rowBase = mblk * 128;
  const int col0 = nblk * 128;
  const int task = nblk >> 1;

  // staging source (inverse 16-B-slot swizzle, r13-proven)
  const int srow = tid >> 3;
  const int soff = ((tid & 7) ^ ((tid >> 3) & 7)) * 16;
  const unsigned char* pA = Xq + (size_t)(rowBase + srow) * KDIM + soff;
  const unsigned char* pB = Wq + (size_t)(col0 + srow) * KDIM + soff;

  // LDS read bases (8 VGPRs): per region x ks, lo/hi 16-B halves.
  // row = region + mi*32 + l31 (row&7 = l31&7); {buf, mi} via immediates.
  const int rowA = (wr * 64 + l31) * 128;
  const int rowB = 16384 + (wc * 64 + l31) * 128;
  const char* aL0 = sm + rowA + (((l2 * 2) ^ l7) * 16);
  const char* aH0 = sm + rowA + (((l2 * 2 + 1) ^ l7) * 16);
  const char* aL1 = sm + rowA + (((4 + l2 * 2) ^ l7) * 16);
  const char* aH1 = sm + rowA + (((4 + l2 * 2 + 1) ^ l7) * 16);
  const char* bL0 = sm + rowB + (((l2 * 2) ^ l7) * 16);
  const char* bH0 = sm + rowB + (((l2 * 2 + 1) ^ l7) * 16);
  const char* bL1 = sm + rowB + (((4 + l2 * 2) ^ l7) * 16);
  const char* bH1 = sm + rowB + (((4 + l2 * 2 + 1) ^ l7) * 16);

  f32x16 acc[2][2] = {};

  // 8 loads/thread/K-tile into buf B_: A chunks 0..3 (128 rows), B chunks 0..3
#define STG(B_, kB) do { \
    _Pragma("unroll") for (int ii = 0; ii < 4; ++ii) { \
      gload_lds16(pA + (size_t)ii * 32 * KDIM + (kB), sm + (B_) * 32768 + ii * 4096 + tid * 16); \
      gload_lds16(pB + (size_t)ii * 32 * KDIM + (kB), sm + (B_) * 32768 + 16384 + ii * 4096 + tid * 16); \
    } } while (0)

  // 32-B fragment: two b128 at swizzled slots, shufflevector combine (no UB)
#define LD32(dst, lo, hi, off_) do { \
    i32x4 lo_ = *(const i32x4*)((lo) + (off_)); \
    i32x4 hi_ = *(const i32x4*)((hi) + (off_)); \
    (dst) = __builtin_shufflevector(lo_, hi_, 0, 1, 2, 3, 4, 5, 6, 7); \
  } while (0)

#define KSTEP(B_, aL, aH, bL, bH) do { \
    i32x8 aF0, aF1, bF0, bF1; \
    LD32(aF0, aL, aH, (B_) * 32768); \
    LD32(aF1, aL, aH, (B_) * 32768 + 4096); \
    LD32(bF0, bL, bH, (B_) * 32768); \
    LD32(bF1, bL, bH, (B_) * 32768 + 4096); \
    __builtin_amdgcn_s_setprio(1); \
    MFMA_(aF0, bF0, acc[0][0]); MFMA_(aF0, bF1, acc[0][1]); \
    MFMA_(aF1, bF0, acc[1][0]); MFMA_(aF1, bF1, acc[1][1]); \
    __builtin_amdgcn_s_setprio(0); \
  } while (0)

  // Per K-tile: {ks0 + ks1 (4 frag loads + 4 MFMA each); LGKM0; BAR;
  //              STG t+2 -> own buf; VMC(8) [t+1 resident]; BAR}.
#define KTILE(B_, kB2) do { \
    KSTEP(B_, aL0, aH0, bL0, bH0); \
    KSTEP(B_, aL1, aH1, bL1, bH1); \
    LGKM0(); SCHED0(); \
    BAR(); \
    STG(B_, kB2); \
    VMC(8); SCHED0(); \
    BAR(); \
  } while (0)

  // prologue: tile0 -> buf0, tile1 -> buf1; VMC(8) -> tile0 resident
  STG(0, 0);
  STG(1, 128);
  VMC(8); SCHED0();
  BAR();

#pragma unroll 1
  for (int kt = 0; kt < 8; kt += 2) {
    const int k2 = (kt + 2 < 8) ? (kt + 2) * 128 : 0;   // bytes (fp8)
    const int k3 = (kt + 3 < 8) ? (kt + 3) * 128 : 0;
    KTILE(0, k2);
    KTILE(1, k3);
  }

  // Drain wrap-garbage stages before reusing LDS / ending the block (r5 race).
  VMC(0); SCHED0();
  BAR();

  // epilogue: per-row max-dot over 2 n-tiles + 32 col-lanes -> red -> atomic.
  // C/D layout (r13 HW-verified): col=lane&31, row=(reg&3)+8*(reg>>2)+4*l2.
  float (*red)[2] = (float (*)[2])(sm + 65536);  // outside staging regions
#pragma unroll
  for (int mi = 0; mi < 2; ++mi) {
#pragma unroll
    for (int r = 0; r < 16; ++r) {
      float v = fmaxf(acc[mi][0][r], acc[mi][1][r]);
      v = fmaxf(v, __shfl_xor(v, 1, 64));
      v = fmaxf(v, __shfl_xor(v, 2, 64));
      v = fmaxf(v, __shfl_xor(v, 4, 64));
      v = fmaxf(v, __shfl_xor(v, 8, 64));
      v = fmaxf(v, __shfl_xor(v, 16, 64));
      if (l31 == 0)
        red[wr * 64 + mi * 32 + (r & 3) + 8 * (r >> 2) + 4 * l2][wc] = v;
    }
  }
  BAR();
  if (tid < 128) {
    const float vv = fmaxf(red[tid][0], red[tid][1]);
    const float d = sqrtf(fmaxf(2.0f - 2.0f * vv, 1e-12f));
    // all published values negative: uint atomicMin == float max == -min dist
    atomicMin((unsigned int*)&out[(size_t)(rowBase + tid) * TASKS + task],
              __float_as_uint(-d));
  }
#undef KTILE
#undef KSTEP
#undef LD32
#undef STG
}

extern "C" void kernel_launch(void* const* d_in, const int* in_sizes, int n_in,
                              void* d_out, int out_size, void* d_ws, size_t ws_size,
                              hipStream_t stream) {
  const float* X = (const float*)d_in[0];   // (8192, 1024) fp32
  const float* W = (const float*)d_in[1];   // (5120, 1024) fp32
  float* out = (float*)d_out;               // (8192, 20) fp32

  unsigned char* Xq = (unsigned char*)d_ws;                          // 8.4 MB fp8
  unsigned char* Wq = Xq + (size_t)M_TOTAL * KDIM;                   // 5.2 MB fp8

  norm_rows_kernel<<<M_TOTAL + TASKS * SBUF, 256, 0, stream>>>(
      X, W, (unsigned int*)Xq, (unsigned int*)Wq, out);
  gemm_min_kernel<<<2560, 256, 0, stream>>>(Xq, Wq, out);
}

// Round 21
// 90.088 us; speedup vs baseline: 1.0717x; 1.0651x over previous
//
#include <hip/hip_runtime.h>

#define M_TOTAL 8192
#define KDIM 1024
#define TASKS 20
#define SBUF 256

typedef __attribute__((ext_vector_type(4))) int i32x4;
typedef __attribute__((ext_vector_type(8))) int i32x8;
typedef __attribute__((ext_vector_type(16))) float f32x16;

__device__ __forceinline__ void gload_lds16(const void* g, char* l) {
  __builtin_amdgcn_global_load_lds((const __attribute__((address_space(1))) void*)g,
                                   (__attribute__((address_space(3))) void*)l, 16, 0, 0);
}

#define FENCE() asm volatile("" ::: "memory")
#define BAR() do { FENCE(); __builtin_amdgcn_s_barrier(); FENCE(); } while (0)
#define LGKM0() asm volatile("s_waitcnt lgkmcnt(0)" ::: "memory")
#define VMC(n) asm volatile("s_waitcnt vmcnt(" #n ")" ::: "memory")
#define SCHED0() __builtin_amdgcn_sched_barrier(0)
// All scale bytes = 0x7F (E8M0 exp 0 -> x1.0): plain fp8 GEMM at MX rate.
#define MFMA_(a, bb, c) \
  (c) = __builtin_amdgcn_mfma_scale_f32_32x32x64_f8f6f4((a), (bb), (c), 0, 0, \
                                                        0, 0x7F7F7F7F, 0, 0x7F7F7F7F)

// One block per row: L2-normalize a 1024-float row of X or W, emit fp8 e4m3
// (RNE via v_cvt_pk_fp8_f32). First 640 blocks also init out[] to -1e30 for
// the atomicMin combine (runs before gemm in stream order).
__global__ __launch_bounds__(256) void norm_rows_kernel(const float* __restrict__ X,
                                                        const float* __restrict__ W,
                                                        unsigned int* __restrict__ Xq,
                                                        unsigned int* __restrict__ Wq,
                                                        float* __restrict__ out) {
  const int row = blockIdx.x;
  const int tid = threadIdx.x;
  if (row < (M_TOTAL * TASKS) / 256) out[row * 256 + tid] = -1e30f;
  const float* in;
  unsigned int* outp;
  int r;
  if (row < M_TOTAL) { in = X; outp = Xq; r = row; }
  else               { in = W; outp = Wq; r = row - M_TOTAL; }
  const float4 v = ((const float4*)(in + (size_t)r * KDIM))[tid];
  float s = v.x * v.x + v.y * v.y + v.z * v.z + v.w * v.w;
#pragma unroll
  for (int off = 32; off >= 1; off >>= 1) s += __shfl_xor(s, off, 64);
  __shared__ float part[4];
  if ((tid & 63) == 0) part[tid >> 6] = s;
  __syncthreads();
  s = part[0] + part[1] + part[2] + part[3];
  const float sc = rsqrtf(s);
  int pk = __builtin_amdgcn_cvt_pk_fp8_f32(v.x * sc, v.y * sc, 0, false);
  pk = __builtin_amdgcn_cvt_pk_fp8_f32(v.z * sc, v.w * sc, pk, true);
  outp[(size_t)r * (KDIM / 4) + tid] = (unsigned int)pk;
}

// 128(M) x 128(N) x BK=64 fp8-MX tile, 32x32x64 shape (operand/C-D layouts
// HW-verified r13). 256 thr = 4 waves (2M x 2N), wave tile 64x64, acc[2][2].
// *** r20 change: BK 128->64 on the VERIFIED 2-barrier template (parameter
// change, not a sync edit). LDS/block 33.8 KB -> 3 blocks/CU (reg-capped:
// ~168/wave incl. acc -> 3 waves/SIMD) = 3 independent barrier domains vs 2.
// All fp8 rounds ran 2 domains at 19% MfmaUtil; the idle is sync-envelope,
// which extra out-of-phase domains absorb. 16 K-tiles, one MFMA k-window
// each; VMC(4) counted ledger, 2-deep. ***
// Rows are 64 B -> pair-row swizzle: rows 2q,2q+1 share a 128-B line; phys
// 16-B slot of (row, s) = (((row&1)<<2)|s) ^ (q&7). Write decode is
// byte-identical to the 7x-HW-proven bf16 rounds (r3-r9):
// s8=(t&7)^((t>>3)&7), row=2*(t>>3)+(s8>>2), byte (s8&3)*16. Read pattern is
// quarter-wave 2-way per 16-B slot column (free, m136) — same profile as the
// measured-zero-conflict bf16 rounds (r19's full-wave 8-way count was the
// wrong analysis unit). Fragment = lo/hi b128 + shufflevector (r10 TBAA).
// LDS per buf (16 KB at B_*16384): A [0,8K) (wr*4096 + mi*2048 + line*128),
// B [8K,16K). red at [32768,33792) — outside staging (r5 race lesson).
// Half-task columns combined via uint atomicMin of negative floats (exact).
__global__ __launch_bounds__(256, 1) void gemm_min_kernel(const unsigned char* __restrict__ Xq,
                                                          const unsigned char* __restrict__ Wq,
                                                          float* __restrict__ out) {
  __shared__ __align__(32) char sm[33792];

  const int tid = threadIdx.x;
  const int lane = tid & 63;
  const int w = tid >> 6, wr = w >> 1, wc = w & 1;
  const int l31 = lane & 31, l2 = lane >> 5;
  const int q7 = (l31 >> 1) & 7;   // line index low bits
  const int h4 = (l31 & 1) << 2;   // row parity -> phys bit2

  // XCD swizzle: 2560 blocks; xcd owns an 8-mblk stripe, mblk fastest, nblk slow.
  const int o = blockIdx.x;
  const int xcd = o & 7, i = o >> 3;        // i in [0,320)
  const int nblk = i >> 3;                   // 0..39
  const int mblk = xcd * 8 + (i & 7);        // 0..63
  const int rowBase = mblk * 128;
  const int col0 = nblk * 128;
  const int task = nblk >> 1;

  // staging source decode (inverse pair-row swizzle, r3-r9 proven algebra)
  const int s8 = (tid & 7) ^ ((tid >> 3) & 7);
  const int rowl = 2 * (tid >> 3) + (s8 >> 2);   // 0..63 within a 64-row chunk
  const int koff = (s8 & 3) * 16;                // byte offset within the 64-B row
  const unsigned char* pA = Xq + (size_t)(rowBase + rowl) * KDIM + koff;
  const unsigned char* pB = Wq + (size_t)(col0 + rowl) * KDIM + koff;

  // LDS read bases (4 VGPRs); {buf +16384, mi +2048} via ds immediates.
  // A row = wr*64 + mi*32 + l31 -> byte wr*4096 + mi*2048 + (l31>>1)*128 + phys*16.
  const int baseRow = (l31 >> 1) * 128;
  const char* aL = sm + wr * 4096 + baseRow + (((h4 | (l2 * 2)) ^ q7) * 16);
  const char* aH = sm + wr * 4096 + baseRow + (((h4 | (l2 * 2 + 1)) ^ q7) * 16);
  const char* bL = sm + 8192 + wc * 4096 + baseRow + (((h4 | (l2 * 2)) ^ q7) * 16);
  const char* bH = sm + 8192 + wc * 4096 + baseRow + (((h4 | (l2 * 2 + 1)) ^ q7) * 16);

  f32x16 acc[2][2] = {};

  // 4 loads/thread/K-tile into buf B_: A chunks ii=0,1 (128 rows), B same.
#define STG(B_, kB) do { \
    gload_lds16(pA + (kB), sm + (B_) * 16384 + tid * 16); \
    gload_lds16(pA + (size_t)64 * KDIM + (kB), sm + (B_) * 16384 + 4096 + tid * 16); \
    gload_lds16(pB + (kB), sm + (B_) * 16384 + 8192 + tid * 16); \
    gload_lds16(pB + (size_t)64 * KDIM + (kB), sm + (B_) * 16384 + 12288 + tid * 16); \
  } while (0)

  // 32-B fragment: two b128 at swizzled slots, shufflevector combine (no UB)
#define LD32(dst, lo, hi, off_) do { \
    i32x4 lo_ = *(const i32x4*)((lo) + (off_)); \
    i32x4 hi_ = *(const i32x4*)((hi) + (off_)); \
    (dst) = __builtin_shufflevector(lo_, hi_, 0, 1, 2, 3, 4, 5, 6, 7); \
  } while (0)

  // Per K-tile t (buf B_ = t&1): {8 b128 frag reads; 4 MFMA; LGKM0 (all waves
  //  done reading buf B_); BAR; STG t+2 -> own buf (parity); VMC(4) [t+1
  //  resident, t+2's 4 loads stay in flight]; BAR}. r17-verified schedule.
#define KTILE(B_, kB2) do { \
    i32x8 aF0, aF1, bF0, bF1; \
    LD32(aF0, aL, aH, (B_) * 16384); \
    LD32(aF1, aL, aH, (B_) * 16384 + 2048); \
    LD32(bF0, bL, bH, (B_) * 16384); \
    LD32(bF1, bL, bH, (B_) * 16384 + 2048); \
    __builtin_amdgcn_s_setprio(1); \
    MFMA_(aF0, bF0, acc[0][0]); MFMA_(aF0, bF1, acc[0][1]); \
    MFMA_(aF1, bF0, acc[1][0]); MFMA_(aF1, bF1, acc[1][1]); \
    __builtin_amdgcn_s_setprio(0); \
    LGKM0(); SCHED0(); \
    BAR(); \
    STG(B_, kB2); \
    VMC(4); SCHED0(); \
    BAR(); \
  } while (0)

  // prologue: tile0 -> buf0, tile1 -> buf1; VMC(4) -> tile0 resident,
  // tile1's 4 loads in flight; barrier.
  STG(0, 0);
  STG(1, 64);
  VMC(4); SCHED0();
  BAR();

  // 16 K-tiles of 64 B each; wrap stages harmless garbage (drained below).
#pragma unroll 1
  for (int kt = 0; kt < 16; kt += 2) {
    const int k2 = (kt + 2 < 16) ? (kt + 2) * 64 : 0;
    const int k3 = (kt + 3 < 16) ? (kt + 3) * 64 : 0;
    KTILE(0, k2);
    KTILE(1, k3);
  }

  // Drain wrap-garbage stages before reusing LDS / ending the block (r5 race).
  VMC(0); SCHED0();
  BAR();

  // epilogue: per-row max-dot over 2 n-tiles + 32 col-lanes -> red -> atomic.
  // C/D layout (r13 HW-verified): col=lane&31, row=(reg&3)+8*(reg>>2)+4*l2.
  float (*red)[2] = (float (*)[2])(sm + 32768);  // outside staging regions
#pragma unroll
  for (int mi = 0; mi < 2; ++mi) {
#pragma unroll
    for (int r = 0; r < 16; ++r) {
      float v = fmaxf(acc[mi][0][r], acc[mi][1][r]);
      v = fmaxf(v, __shfl_xor(v, 1, 64));
      v = fmaxf(v, __shfl_xor(v, 2, 64));
      v = fmaxf(v, __shfl_xor(v, 4, 64));
      v = fmaxf(v, __shfl_xor(v, 8, 64));
      v = fmaxf(v, __shfl_xor(v, 16, 64));
      if (l31 == 0)
        red[wr * 64 + mi * 32 + (r & 3) + 8 * (r >> 2) + 4 * l2][wc] = v;
    }
  }
  BAR();
  if (tid < 128) {
    const float vv = fmaxf(red[tid][0], red[tid][1]);
    const float d = sqrtf(fmaxf(2.0f - 2.0f * vv, 1e-12f));
    // all published values negative: uint atomicMin == float max == -min dist
    atomicMin((unsigned int*)&out[(size_t)(rowBase + tid) * TASKS + task],
              __float_as_uint(-d));
  }
#undef KTILE
#undef LD32
#undef STG
}

extern "C" void kernel_launch(void* const* d_in, const int* in_sizes, int n_in,
                              void* d_out, int out_size, void* d_ws, size_t ws_size,
                              hipStream_t stream) {
  const float* X = (const float*)d_in[0];   // (8192, 1024) fp32
  const float* W = (const float*)d_in[1];   // (5120, 1024) fp32
  float* out = (float*)d_out;               // (8192, 20) fp32

  unsigned char* Xq = (unsigned char*)d_ws;                          // 8.4 MB fp8
  unsigned char* Wq = Xq + (size_t)M_TOTAL * KDIM;                   // 5.2 MB fp8

  norm_rows_kernel<<<M_TOTAL + TASKS * SBUF, 256, 0, stream>>>(
      X, W, (unsigned int*)Xq, (unsigned int*)Wq, out);
  gemm_min_kernel<<<2560, 256, 0, stream>>>(Xq, Wq, out);
}